// Round 5
// baseline (93.433 us; speedup 1.0000x reference)
//
#include <hip/hip_runtime.h>
#include <math.h>

#define BB 4
#define HH 128
#define WW 128
#define CIN 64
#define COUT 64
#define KK 9
#define OMC 27
#define NPIX (BB * HH * WW)

typedef __attribute__((ext_vector_type(8))) short bf16x8;
typedef __attribute__((ext_vector_type(4))) float f32x4;

static __device__ __forceinline__ unsigned short f2bf(float f) {
    unsigned int u = __float_as_uint(f);
    unsigned int r = (u + 0x7fffu + ((u >> 16) & 1u)) >> 16;
    return (unsigned short)r;
}

static __device__ __forceinline__ unsigned int pk2(float a, float b) {
    return (unsigned int)f2bf(a) | ((unsigned int)f2bf(b) << 16);
}

// ---------------------------------------------------------------------------
// Kernel 0: one-shot transform of wmain f32 [576 k][64 n] into bf16 MFMA
// B-frag-ready layout (16B/lane coalesced loads in the main kernel).
// ---------------------------------------------------------------------------
__global__ __launch_bounds__(64) void wb_transform(
    const float* __restrict__ wmain, uint4* __restrict__ wb)
{
    const int tid  = blockIdx.x * 64 + threadIdx.x;  // [0, 18*4*64)
    const int lane = tid & 63;
    const int nf   = (tid >> 6) & 3;
    const int ks   = tid >> 8;
    const int k0   = ks * 32 + ((lane >> 4) * 8);
    const int n    = nf * 16 + (lane & 15);
    unsigned short v[8];
    #pragma unroll
    for (int j = 0; j < 8; ++j) v[j] = f2bf(wmain[(size_t)(k0 + j) * COUT + n]);
    uint4 q;
    q.x = (unsigned int)v[0] | ((unsigned int)v[1] << 16);
    q.y = (unsigned int)v[2] | ((unsigned int)v[3] << 16);
    q.z = (unsigned int)v[4] | ((unsigned int)v[5] << 16);
    q.w = (unsigned int)v[6] | ((unsigned int)v[7] << 16);
    wb[tid] = q;
}

// ---------------------------------------------------------------------------
// Kernel 1: offset/mask conv as bf16 MFMA implicit GEMM.  Epilogue fuses the
// deformable prep: j<18 -> absolute sampling coords, j>=18 -> sigmoid(mask).
// ---------------------------------------------------------------------------
__global__ __launch_bounds__(256) void offset_conv_mfma(
    const float* __restrict__ x,
    const float* __restrict__ wofs,
    const float* __restrict__ bofs,
    float* __restrict__ om)
{
    __shared__ char lds[16384 + 36864];
    char* xs = lds;
    char* ws = lds + 16384;

    const int tid  = threadIdx.x;
    const int lane = tid & 63;
    const int wv   = tid >> 6;
    const int bid = ((blockIdx.x & 7) << 6) + (blockIdx.x >> 3);  // XCD chunk
    const int b = bid >> 7;
    const int h = bid & (HH - 1);
    const float* xrow0 = x + (size_t)b * HH * WW * CIN;

    #pragma unroll
    for (int r = 0; r < 9; ++r) {
        const int t  = r;
        const int j  = (tid >> 3) & 31;
        const int c8 = tid & 7;
        unsigned short v[8];
        if (j < OMC) {
            const float* wp = wofs + ((size_t)t * CIN + c8 * 8) * OMC + j;
            #pragma unroll
            for (int i = 0; i < 8; ++i) v[i] = f2bf(wp[i * OMC]);
        } else {
            #pragma unroll
            for (int i = 0; i < 8; ++i) v[i] = 0;
        }
        uint4 q;
        q.x = (unsigned int)v[0] | ((unsigned int)v[1] << 16);
        q.y = (unsigned int)v[2] | ((unsigned int)v[3] << 16);
        q.z = (unsigned int)v[4] | ((unsigned int)v[5] << 16);
        q.w = (unsigned int)v[6] | ((unsigned int)v[7] << 16);
        const int off = (((t * 32 + j) * 128) + c8 * 16) ^ ((j & 7) << 4);
        *(uint4*)(ws + off) = q;
    }

    f32x4 acc[2][2] = {};
    const int w0 = wv * 32;

    for (int ty = 0; ty < 3; ++ty) {
        const int hy = h - 1 + ty;
        const bool vrow = (hy >= 0) && (hy < HH);
        __syncthreads();
        if (vrow) {
            const float* src = xrow0 + (size_t)hy * WW * CIN;
            #pragma unroll
            for (int r = 0; r < 4; ++r) {
                const int ch = tid + 256 * r;
                const int c8 = ch & 7;
                const int w  = ch >> 3;
                const float* p = src + (size_t)w * CIN + c8 * 8;
                float4 a0 = *(const float4*)p;
                float4 a1 = *(const float4*)(p + 4);
                uint4 q;
                q.x = pk2(a0.x, a0.y);
                q.y = pk2(a0.z, a0.w);
                q.z = pk2(a1.x, a1.y);
                q.w = pk2(a1.z, a1.w);
                const int off = (w * 128 + c8 * 16) ^ ((w & 7) << 4);
                *(uint4*)(xs + off) = q;
            }
        }
        __syncthreads();
        if (!vrow) continue;

        #pragma unroll
        for (int tx = 0; tx < 3; ++tx) {
            const int t = ty * 3 + tx;
            #pragma unroll
            for (int ch2 = 0; ch2 < 2; ++ch2) {
                bf16x8 bfr[2];
                #pragma unroll
                for (int nf = 0; nf < 2; ++nf) {
                    const int j = nf * 16 + (lane & 15);
                    const int off = (((t * 32 + j) * 128) + ch2 * 64 + ((lane >> 4) * 16))
                                    ^ ((j & 7) << 4);
                    bfr[nf] = *(const bf16x8*)(ws + off);
                }
                bf16x8 afr[2];
                #pragma unroll
                for (int m = 0; m < 2; ++m) {
                    const int wp = w0 + m * 16 + (lane & 15) + tx - 1;
                    const bool vv = (wp >= 0) && (wp < WW);
                    const int wc = vv ? wp : 0;
                    const int off = (wc * 128 + ch2 * 64 + ((lane >> 4) * 16))
                                    ^ ((wc & 7) << 4);
                    bf16x8 a = *(const bf16x8*)(xs + off);
                    if (!vv) a = (bf16x8)(short)0;
                    afr[m] = a;
                }
                acc[0][0] = __builtin_amdgcn_mfma_f32_16x16x32_bf16(afr[0], bfr[0], acc[0][0], 0, 0, 0);
                acc[0][1] = __builtin_amdgcn_mfma_f32_16x16x32_bf16(afr[0], bfr[1], acc[0][1], 0, 0, 0);
                acc[1][0] = __builtin_amdgcn_mfma_f32_16x16x32_bf16(afr[1], bfr[0], acc[1][0], 0, 0, 0);
                acc[1][1] = __builtin_amdgcn_mfma_f32_16x16x32_bf16(afr[1], bfr[1], acc[1][1], 0, 0, 0);
            }
        }
    }

    const int pixbase = (b * HH + h) * WW;
    #pragma unroll
    for (int nf = 0; nf < 2; ++nf) {
        const int j = nf * 16 + (lane & 15);
        if (j >= OMC) continue;
        const float bb = bofs[j];
        #pragma unroll
        for (int m = 0; m < 2; ++m) {
            const int row0 = w0 + m * 16 + ((lane >> 4) * 4);
            #pragma unroll
            for (int r = 0; r < 4; ++r) {
                float val = acc[m][nf][r] + bb;
                const int wpix = row0 + r;
                if (j < 18) {
                    const int t = j >> 1;
                    if ((j & 1) == 0) val += (float)(h - 1 + t / 3);     // absolute py
                    else              val += (float)(wpix - 1 + t % 3);  // absolute px
                } else {
                    val = 1.0f / (1.0f + __expf(-val));                  // sigmoid(mask)
                }
                om[(size_t)(pixbase + wpix) * OMC + j] = val;
            }
        }
    }
}

// ---------------------------------------------------------------------------
// Kernel 2: deformable sampling + MFMA, A-fragment gathered DIRECTLY in
// registers (no LDS tile, no per-tap LDS drain).
// Block = 256 thr = 4 waves, 64 px; wave owns 16 contiguous px.
// Lane l: pixel p = l&15, channel group cg = l>>4 (ch 8cg.. / 32+8cg..).
// Per tap: 16 unconditional float4 gathers (corners clamped in-bounds,
// OOB killed via zeroed bilinear weight), 64 FMA, pack -> 2 A-frags ->
// 8 MFMA (B streamed coalesced from wb/L2).  Full 9-tap unroll for ILP.
// ---------------------------------------------------------------------------
#define TM 64

__global__ __launch_bounds__(256, 4) void dcn_main_mfma(
    const float* __restrict__ x,
    const uint4* __restrict__ wb,
    const float* __restrict__ bias,
    const float* __restrict__ om,
    float* __restrict__ out)
{
    __shared__ float om_s[4][432];   // 6912 B

    const int tid  = threadIdx.x;
    const int lane = tid & 63;
    const int wv   = tid >> 6;
    const int bid  = ((blockIdx.x & 7) << 7) + (blockIdx.x >> 3);  // XCD chunk
    const int pix0 = bid * TM;
    const int b    = pix0 >> 14;
    const float* xb = x + (size_t)b * HH * WW * CIN;

    // ---- stage this wave's om slice: 432 contiguous f32 ----
    float* omw = om_s[wv];
    {
        const float* og = om + (size_t)(pix0 + wv * 16) * OMC;
        #pragma unroll
        for (int i = 0; i < 7; ++i) {
            const int idx = i * 64 + lane;
            if (idx < 432) omw[idx] = og[idx];
        }
    }

    const int p  = lane & 15;
    const int cg = lane >> 4;
    const float* omp = omw + p * OMC;
    const int cgo = cg * 8;  // channel offset within ch2-group

    f32x4 acc[4] = {};

    #pragma unroll
    for (int t = 0; t < KK; ++t) {
        const float py  = omp[2 * t];
        const float pxx = omp[2 * t + 1];
        const float mk  = omp[18 + t];

        const float fy = floorf(py), fx = floorf(pxx);
        const int y0 = (int)fy, x0 = (int)fx;
        const float wy1 = py - fy, wx1 = pxx - fx;
        const float wy0 = 1.0f - wy1, wx0 = 1.0f - wx1;
        const bool vy0 = (unsigned)y0 < (unsigned)HH;
        const bool vy1 = (unsigned)(y0 + 1) < (unsigned)HH;
        const bool vx0 = (unsigned)x0 < (unsigned)WW;
        const bool vx1 = (unsigned)(x0 + 1) < (unsigned)WW;
        const float w00 = (vy0 && vx0) ? wy0 * wx0 * mk : 0.0f;
        const float w01 = (vy0 && vx1) ? wy0 * wx1 * mk : 0.0f;
        const float w10 = (vy1 && vx0) ? wy1 * wx0 * mk : 0.0f;
        const float w11 = (vy1 && vx1) ? wy1 * wx1 * mk : 0.0f;
        const int yc0 = min(max(y0, 0), HH - 1);
        const int yc1 = min(max(y0 + 1, 0), HH - 1);
        const int xc0 = min(max(x0, 0), WW - 1);
        const int xc1 = min(max(x0 + 1, 0), WW - 1);

        const float* r00 = xb + (yc0 * WW + xc0) * CIN + cgo;
        const float* r01 = xb + (yc0 * WW + xc1) * CIN + cgo;
        const float* r10 = xb + (yc1 * WW + xc0) * CIN + cgo;
        const float* r11 = xb + (yc1 * WW + xc1) * CIN + cgo;

        // 16 unconditional float4 loads: 4 corners x {ch2=0: +0,+4 ; ch2=1: +32,+36}
        float4 v00a = *(const float4*)(r00);      float4 v00b = *(const float4*)(r00 + 4);
        float4 v00c = *(const float4*)(r00 + 32); float4 v00d = *(const float4*)(r00 + 36);
        float4 v01a = *(const float4*)(r01);      float4 v01b = *(const float4*)(r01 + 4);
        float4 v01c = *(const float4*)(r01 + 32); float4 v01d = *(const float4*)(r01 + 36);
        float4 v10a = *(const float4*)(r10);      float4 v10b = *(const float4*)(r10 + 4);
        float4 v10c = *(const float4*)(r10 + 32); float4 v10d = *(const float4*)(r10 + 36);
        float4 v11a = *(const float4*)(r11);      float4 v11b = *(const float4*)(r11 + 4);
        float4 v11c = *(const float4*)(r11 + 32); float4 v11d = *(const float4*)(r11 + 36);

        float s[16];
        #pragma unroll
        for (int j = 0; j < 4; ++j) {
            s[j]      = w00 * ((const float*)&v00a)[j] + w01 * ((const float*)&v01a)[j]
                      + w10 * ((const float*)&v10a)[j] + w11 * ((const float*)&v11a)[j];
            s[4 + j]  = w00 * ((const float*)&v00b)[j] + w01 * ((const float*)&v01b)[j]
                      + w10 * ((const float*)&v10b)[j] + w11 * ((const float*)&v11b)[j];
            s[8 + j]  = w00 * ((const float*)&v00c)[j] + w01 * ((const float*)&v01c)[j]
                      + w10 * ((const float*)&v10c)[j] + w11 * ((const float*)&v11c)[j];
            s[12 + j] = w00 * ((const float*)&v00d)[j] + w01 * ((const float*)&v01d)[j]
                      + w10 * ((const float*)&v10d)[j] + w11 * ((const float*)&v11d)[j];
        }

        uint4 a0q, a1q;
        a0q.x = pk2(s[0],  s[1]);  a0q.y = pk2(s[2],  s[3]);
        a0q.z = pk2(s[4],  s[5]);  a0q.w = pk2(s[6],  s[7]);
        a1q.x = pk2(s[8],  s[9]);  a1q.y = pk2(s[10], s[11]);
        a1q.z = pk2(s[12], s[13]); a1q.w = pk2(s[14], s[15]);
        const bf16x8 a0 = *(const bf16x8*)&a0q;
        const bf16x8 a1 = *(const bf16x8*)&a1q;

        const uint4* wb0 = wb + (t * 2) * 4 * 64 + lane;
        #pragma unroll
        for (int nf = 0; nf < 4; ++nf) {
            const bf16x8 bfr = *(const bf16x8*)(wb0 + nf * 64);
            acc[nf] = __builtin_amdgcn_mfma_f32_16x16x32_bf16(a0, bfr, acc[nf], 0, 0, 0);
        }
        #pragma unroll
        for (int nf = 0; nf < 4; ++nf) {
            const bf16x8 bfr = *(const bf16x8*)(wb0 + (4 + nf) * 64);
            acc[nf] = __builtin_amdgcn_mfma_f32_16x16x32_bf16(a1, bfr, acc[nf], 0, 0, 0);
        }
    }

    // ---- epilogue: D col = lane&15 -> cout, row = 4*(lane>>4)+r -> pixel ----
    #pragma unroll
    for (int nf = 0; nf < 4; ++nf) {
        const int n  = nf * 16 + (lane & 15);
        const float bs = bias[n];
        const int m0 = wv * 16 + ((lane >> 4) * 4);
        #pragma unroll
        for (int r = 0; r < 4; ++r) {
            out[(size_t)(pix0 + m0 + r) * COUT + n] = acc[nf][r] + bs;
        }
    }
}

extern "C" void kernel_launch(void* const* d_in, const int* in_sizes, int n_in,
                              void* d_out, int out_size, void* d_ws, size_t ws_size,
                              hipStream_t stream)
{
    const float* x     = (const float*)d_in[0];
    const float* wmain = (const float*)d_in[1];
    const float* bias  = (const float*)d_in[2];
    const float* wofs  = (const float*)d_in[3];
    const float* bofs  = (const float*)d_in[4];
    float* out = (float*)d_out;
    float* om  = (float*)d_ws;                                    // 7077888 B
    uint4* wb  = (uint4*)((char*)d_ws + (size_t)NPIX * OMC * 4);  // +73728 B

    wb_transform<<<72, 64, 0, stream>>>(wmain, wb);
    offset_conv_mfma<<<BB * HH, 256, 0, stream>>>(x, wofs, bofs, om);
    dcn_main_mfma<<<NPIX / TM, 256, 0, stream>>>(x, wb, bias, om, out);
}